// Round 1
// baseline (729.271 us; speedup 1.0000x reference)
//
#include <hip/hip_runtime.h>

#define B_ 8
#define C_ 256
#define H_ 96
#define W_ 160
#define TX 8
#define NXG (W_ / TX)   // 20
#define ND 9            // displacements per axis
#define NDISP (ND * ND) // 81

__global__ __launch_bounds__(256) void corr_kernel(
    const float* __restrict__ in1,
    const float* __restrict__ in2,
    float* __restrict__ out)
{
    const int tid = blockIdx.x * 256 + threadIdx.x;
    // decompose: xg fastest (coalescing), then dy, y, b
    const int xg = tid % NXG;
    int t = tid / NXG;
    const int dy = t % ND;
    t /= ND;
    const int y = t % H_;
    const int b = t / H_;

    const int x0 = xg * TX;
    const int yp = y + dy - 4;   // shifted row in input2 (PAD=MD=4)

    // Output base for dx=0: out[b, dy*9+0, y, x0]
    float* outp = out + (((size_t)(b * NDISP + dy * ND) * H_ + y) * W_ + x0);
    const int out_dstride = H_ * W_;   // stride between dx channels

    if (yp < 0 || yp >= H_) {
        // entire shifted row is zero-pad -> all 9*8 outputs are 0
        float4 z = make_float4(0.f, 0.f, 0.f, 0.f);
        #pragma unroll
        for (int dx = 0; dx < ND; ++dx) {
            *reinterpret_cast<float4*>(outp + dx * out_dstride)     = z;
            *reinterpret_cast<float4*>(outp + dx * out_dstride + 4) = z;
        }
        return;
    }

    float acc[ND][TX];
    #pragma unroll
    for (int dx = 0; dx < ND; ++dx)
        #pragma unroll
        for (int j = 0; j < TX; ++j)
            acc[dx][j] = 0.f;

    const int chstride = H_ * W_;
    const float* p1 = in1 + (((size_t)b * C_) * H_ + y)  * W_ + x0;
    const float* p2 = in2 + (((size_t)b * C_) * H_ + yp) * W_ + (x0 - 4);
    // window [x0-4, x0+12): 4 aligned float4 blocks; edges fully in or out
    const bool okL = (x0 - 4) >= 0;     // false only for xg == 0
    const bool okR = (x0 + 12) <= W_;   // false only for xg == NXG-1

    const float4 z4 = make_float4(0.f, 0.f, 0.f, 0.f);

    for (int c = 0; c < C_; ++c) {
        float4 a0 = *reinterpret_cast<const float4*>(p1);
        float4 a1 = *reinterpret_cast<const float4*>(p1 + 4);
        float4 w0 = okL ? *reinterpret_cast<const float4*>(p2)      : z4;
        float4 w1 =       *reinterpret_cast<const float4*>(p2 + 4);
        float4 w2 =       *reinterpret_cast<const float4*>(p2 + 8);
        float4 w3 = okR ? *reinterpret_cast<const float4*>(p2 + 12) : z4;

        float a[TX] = {a0.x, a0.y, a0.z, a0.w, a1.x, a1.y, a1.z, a1.w};
        float w[16] = {w0.x, w0.y, w0.z, w0.w, w1.x, w1.y, w1.z, w1.w,
                       w2.x, w2.y, w2.z, w2.w, w3.x, w3.y, w3.z, w3.w};

        #pragma unroll
        for (int dx = 0; dx < ND; ++dx)
            #pragma unroll
            for (int j = 0; j < TX; ++j)
                acc[dx][j] += a[j] * w[dx + j];

        p1 += chstride;
        p2 += chstride;
    }

    const float s = 1.0f / (float)C_;  // mean over channels (kernel_size=1)
    #pragma unroll
    for (int dx = 0; dx < ND; ++dx) {
        float4 o0 = make_float4(acc[dx][0] * s, acc[dx][1] * s,
                                acc[dx][2] * s, acc[dx][3] * s);
        float4 o1 = make_float4(acc[dx][4] * s, acc[dx][5] * s,
                                acc[dx][6] * s, acc[dx][7] * s);
        *reinterpret_cast<float4*>(outp + dx * out_dstride)     = o0;
        *reinterpret_cast<float4*>(outp + dx * out_dstride + 4) = o1;
    }
}

extern "C" void kernel_launch(void* const* d_in, const int* in_sizes, int n_in,
                              void* d_out, int out_size, void* d_ws, size_t ws_size,
                              hipStream_t stream) {
    const float* in1 = (const float*)d_in[0];
    const float* in2 = (const float*)d_in[1];
    float* out = (float*)d_out;

    const int total_threads = B_ * H_ * ND * NXG;  // 138240
    const int block = 256;
    const int grid = total_threads / block;        // 540 exactly
    corr_kernel<<<grid, block, 0, stream>>>(in1, in2, out);
}